// Round 1
// baseline (202.095 us; speedup 1.0000x reference)
//
#include <hip/hip_runtime.h>
#include <math.h>

#define NCL  27
#define CCH  512
#define HWPX 9216            // 96*96
#define NB   16
#define NPIX (NB * HWPX)     // 147456
#define EPSN 1e-12f

// ---------------------------------------------------------------------------
// k0: per-cluster inverse L2 norm (27 rows of 512) + zero the loss accumulator
// grid = 27 blocks, block = 64 (one wave)
// ---------------------------------------------------------------------------
__global__ __launch_bounds__(64) void k0_prep(const float* __restrict__ cl,
                                              float* __restrict__ inv_cln,
                                              float* __restrict__ loss_acc) {
    const int n = blockIdx.x;
    const int t = threadIdx.x;           // 0..63
    const float* row = cl + n * CCH;
    float ss = 0.f;
#pragma unroll
    for (int i = 0; i < CCH / 64; ++i) {
        float v = row[i * 64 + t];
        ss = fmaf(v, v, ss);
    }
#pragma unroll
    for (int off = 32; off > 0; off >>= 1)
        ss += __shfl_xor(ss, off, 64);
    if (t == 0) {
        inv_cln[n] = 1.0f / fmaxf(sqrtf(ss), EPSN);
        if (n == 0) loss_acc[0] = 0.f;
    }
}

// ---------------------------------------------------------------------------
// k1: main fused kernel. One thread per (b,h,w) pixel.
//  - coalesced x loads (64 lanes span contiguous w)
//  - cluster matrix read via wave-uniform addresses -> scalar loads (L2-hit)
//  - fused softmax + prob store + block-reduced loss atomicAdd
// grid = NPIX/256, block = 256
// ---------------------------------------------------------------------------
__global__ __launch_bounds__(256) void k1_main(const float* __restrict__ x,
                                               const float* __restrict__ cl,
                                               const float* __restrict__ alpha_p,
                                               const float* __restrict__ inv_cln,
                                               float* __restrict__ out,
                                               float* __restrict__ loss_acc) {
    const int p  = blockIdx.x * 256 + threadIdx.x;   // pixel id, exact grid
    const int b  = p / HWPX;                         // uniform within a block
    const int hw = p - b * HWPX;
    const float* xb = x + (size_t)b * (CCH * HWPX) + hw;

    float acc[NCL];
#pragma unroll
    for (int n = 0; n < NCL; ++n) acc[n] = 0.f;
    float ss = 0.f;

    for (int c0 = 0; c0 < CCH; c0 += 8) {
        float xv[8];
#pragma unroll
        for (int i = 0; i < 8; ++i)
            xv[i] = xb[(size_t)(c0 + i) * HWPX];
#pragma unroll
        for (int i = 0; i < 8; ++i)
            ss = fmaf(xv[i], xv[i], ss);
#pragma unroll
        for (int n = 0; n < NCL; ++n) {
            const float* cr = cl + n * CCH + c0;     // uniform -> s_load
            float a = acc[n];
#pragma unroll
            for (int i = 0; i < 8; ++i)
                a = fmaf(xv[i], cr[i], a);
            acc[n] = a;
        }
    }

    const float inv_x  = 1.0f / fmaxf(sqrtf(ss), EPSN);
    const float alpha  = alpha_p[0];

    float ip[NCL];
    float m = -1e30f;
#pragma unroll
    for (int n = 0; n < NCL; ++n) {
        ip[n] = acc[n] * inv_cln[n] * inv_x;         // cosine similarity
        float s = ip[n] * alpha;
        acc[n] = s;
        m = fmaxf(m, s);
    }
    float sum = 0.f;
#pragma unroll
    for (int n = 0; n < NCL; ++n) {
        float e = __expf(acc[n] - m);
        acc[n] = e;
        sum += e;
    }
    const float inv_sum = 1.0f / sum;

    float lterm = 0.f;
    float* ob = out + 1 + (size_t)b * (NCL * HWPX) + hw;
#pragma unroll
    for (int n = 0; n < NCL; ++n) {
        float pr = acc[n] * inv_sum;
        ob[(size_t)n * HWPX] = pr;                   // coalesced per n
        lterm = fmaf(pr, ip[n], lterm);
    }

    // block reduction of loss contribution, one atomic per block
#pragma unroll
    for (int off = 32; off > 0; off >>= 1)
        lterm += __shfl_down(lterm, off, 64);
    __shared__ float wsum[4];
    const int lane = threadIdx.x & 63;
    const int wid  = threadIdx.x >> 6;
    if (lane == 0) wsum[wid] = lterm;
    __syncthreads();
    if (threadIdx.x == 0)
        atomicAdd(loss_acc, wsum[0] + wsum[1] + wsum[2] + wsum[3]);
}

// ---------------------------------------------------------------------------
// k2: finalize loss
// ---------------------------------------------------------------------------
__global__ void k2_fin(const float* __restrict__ loss_acc,
                       float* __restrict__ out) {
    out[0] = -loss_acc[0] * (1.0f / (float)NPIX);
}

extern "C" void kernel_launch(void* const* d_in, const int* in_sizes, int n_in,
                              void* d_out, int out_size, void* d_ws, size_t ws_size,
                              hipStream_t stream) {
    const float* x     = (const float*)d_in[0];
    const float* cl    = (const float*)d_in[1];
    const float* alpha = (const float*)d_in[2];
    float* out = (float*)d_out;
    float* ws  = (float*)d_ws;

    float* inv_cln  = ws;        // 27 floats
    float* loss_acc = ws + 32;   // 1 float

    hipLaunchKernelGGL(k0_prep, dim3(NCL), dim3(64), 0, stream, cl, inv_cln, loss_acc);
    hipLaunchKernelGGL(k1_main, dim3(NPIX / 256), dim3(256), 0, stream,
                       x, cl, alpha, inv_cln, out, loss_acc);
    hipLaunchKernelGGL(k2_fin, dim3(1), dim3(1), 0, stream, loss_acc, out);
}